// Round 1
// baseline (1965.952 us; speedup 1.0000x reference)
//
#include <hip/hip_runtime.h>
#include <stdint.h>

// Instant-NGP hash-grid + MLP, fp32-exact where it matters.
// Kernel A (encode): level-major grid -> per-XCD L2 holds the active 4MiB table.
// Kernel B (mlp): per-thread fp32 MLP, weights via wave-uniform scalar loads,
//                 h1 handed off through per-thread-column LDS as packed bf16.

#define NLV 32
#define LOG2T 19
#define TSZ (1u << LOG2T)
#define TMASK (TSZ - 1u)

typedef float v2f __attribute__((ext_vector_type(2)));

__device__ __forceinline__ uint32_t pack_bf16(float a, float b) {
  // round-to-nearest-even f32->bf16, packed low|high (inputs are finite, >=0 post-relu)
  uint32_t ua = __float_as_uint(a), ub = __float_as_uint(b);
  ua = (ua + 0x7fffu + ((ua >> 16) & 1u)) >> 16;
  ub = (ub + 0x7fffu + ((ub >> 16) & 1u)) >> 16;
  return ua | (ub << 16);
}

__global__ __launch_bounds__(256) void encode_kernel(
    const float* __restrict__ x, const float* __restrict__ emb,
    v2f* __restrict__ feats, int offset, int count, int chunkCap)
{
  const int l = (int)blockIdx.y;
  // scale = float(2^l - 1.0) computed in double, like the reference
  const float scale = (float)((double)(1ULL << l) - 1.0);
  const uint32_t r = 1u << l;
  const bool dense = (l <= 6);  // res^3 <= T exactly for l<=6 with these params
  const v2f* __restrict__ embl = (const v2f*)(emb + ((size_t)l << (LOG2T + 1)));

  #pragma unroll
  for (int k = 0; k < 4; ++k) {
    int li = (int)blockIdx.x * 1024 + k * 256 + (int)threadIdx.x;
    if (li < count) {
      int p = offset + li;
      float xv = x[3 * p + 0], yv = x[3 * p + 1], zv = x[3 * p + 2];
      // EXACT replication of reference: mul RN then add RN (no FMA contraction!)
      float px = __fadd_rn(__fmul_rn(xv, scale), 0.5f);
      float py = __fadd_rn(__fmul_rn(yv, scale), 0.5f);
      float pz = __fadd_rn(__fmul_rn(zv, scale), 0.5f);
      float bx = floorf(px), by = floorf(py), bz = floorf(pz);
      float fx = __fsub_rn(px, bx), fy = __fsub_rn(py, by), fz = __fsub_rn(pz, bz);
      uint32_t gx = (uint32_t)bx, gy = (uint32_t)by, gz = (uint32_t)bz;
      float wx0 = __fsub_rn(1.0f, fx), wx1 = fx;
      float wy0 = __fsub_rn(1.0f, fy), wy1 = fy;
      float wz0 = __fsub_rn(1.0f, fz), wz1 = fz;

      float f0 = 0.0f, f1 = 0.0f;
      #pragma unroll
      for (int c = 0; c < 8; ++c) {
        uint32_t cx = gx + (uint32_t)(c & 1);
        uint32_t cy = gy + (uint32_t)((c >> 1) & 1);
        uint32_t cz = gz + (uint32_t)((c >> 2) & 1);
        uint32_t idx;
        if (dense) idx = cx + cy * r + cz * (r * r);
        else       idx = cx ^ (cy * 2654435761u) ^ (cz * 805459861u);
        idx &= TMASK;
        v2f e = embl[idx];
        float w = ((c & 1) ? wx1 : wx0);
        w = __fmul_rn(w, ((c >> 1) & 1) ? wy1 : wy0);
        w = __fmul_rn(w, ((c >> 2) & 1) ? wz1 : wz0);
        f0 = fmaf(w, e[0], f0);
        f1 = fmaf(w, e[1], f1);
      }
      v2f o; o[0] = f0; o[1] = f1;
      __builtin_nontemporal_store(o, &feats[(size_t)l * (size_t)chunkCap + li]);
    }
  }
}

__global__ __launch_bounds__(256) void mlp_kernel(
    const v2f* __restrict__ feats,
    const float* __restrict__ W1, const float* __restrict__ b1,
    const float* __restrict__ W2, const float* __restrict__ b2,
    const float* __restrict__ W3, const float* __restrict__ b3,
    float* __restrict__ out, int offset, int count, int chunkCap)
{
  // per-thread-column LDS: no cross-thread sharing -> no barriers needed
  __shared__ uint32_t h1p[64][256];  // 64 KiB: 128 bf16 h1 values packed in pairs
  const int tid = (int)threadIdx.x;
  const int li = (int)blockIdx.x * 256 + tid;
  const bool active = (li < count);
  const int lic = active ? li : 0;

  float f[64];
  #pragma unroll
  for (int l = 0; l < 32; ++l) {
    v2f e = __builtin_nontemporal_load(&feats[(size_t)l * (size_t)chunkCap + lic]);
    f[2 * l] = e[0];
    f[2 * l + 1] = e[1];
  }

  // ---- layer 1: h1 = relu(f @ W1 + b1), in 4 output-chunks of 32 ----
  #pragma clang loop unroll(disable)
  for (int jc = 0; jc < 4; ++jc) {
    const float* __restrict__ W1c = W1 + jc * 32;  // wave-uniform -> scalar loads
    const float* __restrict__ b1c = b1 + jc * 32;
    float acc[32];
    #pragma unroll
    for (int jj = 0; jj < 32; ++jj) acc[jj] = b1c[jj];
    #pragma unroll
    for (int k = 0; k < 64; ++k) {
      float fk = f[k];
      #pragma unroll
      for (int jj = 0; jj < 32; ++jj)
        acc[jj] = fmaf(fk, W1c[k * 128 + jj], acc[jj]);
    }
    #pragma unroll
    for (int jj = 0; jj < 32; jj += 2) {
      float a = fmaxf(acc[jj], 0.0f);
      float b = fmaxf(acc[jj + 1], 0.0f);
      h1p[(jc * 32 + jj) >> 1][tid] = pack_bf16(a, b);
    }
  }

  // ---- layer 2 + 3: out = relu(h1 @ W2 + b2) @ W3 + b3, fused ----
  float o = 0.0f;
  #pragma clang loop unroll(disable)
  for (int jc = 0; jc < 4; ++jc) {
    const float* __restrict__ W2c = W2 + jc * 32;
    float acc[32];
    #pragma unroll
    for (int jj = 0; jj < 32; ++jj) acc[jj] = b2[jc * 32 + jj];
    #pragma clang loop unroll_count(2)
    for (int i2 = 0; i2 < 64; ++i2) {
      uint32_t hp = h1p[i2][tid];
      float hlo = __uint_as_float(hp << 16);
      float hhi = __uint_as_float(hp & 0xffff0000u);
      #pragma unroll
      for (int jj = 0; jj < 32; ++jj) {
        acc[jj] = fmaf(hlo, W2c[(2 * i2) * 128 + jj], acc[jj]);
        acc[jj] = fmaf(hhi, W2c[(2 * i2 + 1) * 128 + jj], acc[jj]);
      }
    }
    #pragma unroll
    for (int jj = 0; jj < 32; ++jj)
      o = fmaf(fmaxf(acc[jj], 0.0f), W3[jc * 32 + jj], o);
  }
  if (active) out[offset + li] = o + b3[0];
}

extern "C" void kernel_launch(void* const* d_in, const int* in_sizes, int n_in,
                              void* d_out, int out_size, void* d_ws, size_t ws_size,
                              hipStream_t stream) {
  const float* x   = (const float*)d_in[0];
  const float* emb = (const float*)d_in[1];
  const float* W1  = (const float*)d_in[2];
  const float* b1  = (const float*)d_in[3];
  const float* W2  = (const float*)d_in[4];
  const float* b2  = (const float*)d_in[5];
  const float* W3  = (const float*)d_in[6];
  const float* b3  = (const float*)d_in[7];
  float* out = (float*)d_out;
  const int N = in_sizes[0] / 3;

  v2f* feats = (v2f*)d_ws;
  const size_t perPoint = (size_t)NLV * sizeof(v2f);  // 256 B/point
  size_t capz = ws_size / perPoint;
  if (capz > (size_t)N) capz = (size_t)N;
  int cap = (int)capz & ~1023;
  if (cap <= 0) cap = (N < 1024) ? N : 1024;  // assume ws >= 256 KiB

  for (int off = 0; off < N; off += cap) {
    int cnt = (N - off < cap) ? (N - off) : cap;
    dim3 ge((unsigned)((cnt + 1023) / 1024), NLV);
    encode_kernel<<<ge, 256, 0, stream>>>(x, emb, feats, off, cnt, cap);
    mlp_kernel<<<(cnt + 255) / 256, 256, 0, stream>>>(
        feats, W1, b1, W2, b2, W3, b3, out, off, cnt, cap);
  }
}

// Round 3
// 1964.890 us; speedup vs baseline: 1.0005x; 1.0005x over previous
//
#include <hip/hip_runtime.h>
#include <stdint.h>

// Instant-NGP hash-grid + MLP.
// Kernel A (encode): XCD-owned level partitioning — XCD i (= bid&7) processes
//   levels {i, i+8, i+16, i+24} in sequence, so each XCD's 4MiB L2 holds exactly
//   one active hash table -> gathers become L2 hits.
// Kernel B (mlp): per-thread fp32 MLP, weights via wave-uniform scalar loads,
//   h1 handed off through per-thread-column LDS as packed bf16.
// feats intermediate is packed 2xbf16 per level (halves fabric traffic).

#define NLV 32
#define LOG2T 19
#define TSZ (1u << LOG2T)
#define TMASK (TSZ - 1u)

typedef float v2f __attribute__((ext_vector_type(2)));

__device__ __forceinline__ uint32_t pack_bf16(float a, float b) {
  // round-to-nearest-even f32->bf16, packed a=low | b=high (finite inputs)
  uint32_t ua = __float_as_uint(a), ub = __float_as_uint(b);
  ua = (ua + 0x7fffu + ((ua >> 16) & 1u)) >> 16;
  ub = (ub + 0x7fffu + ((ub >> 16) & 1u)) >> 16;
  return ua | (ub << 16);
}

__global__ __launch_bounds__(256) void encode_kernel(
    const float* __restrict__ x, const float* __restrict__ emb,
    uint32_t* __restrict__ feats, int offset, int count, int chunkCap, int bpl)
{
  // bid -> (xcd, phase, within): level = xcd + 8*phase. Consecutive bids
  // round-robin across the 8 XCDs, so each XCD sees its 4 levels in order.
  const int bid = (int)blockIdx.x;
  const int xcd = bid & 7;
  const int j = bid >> 3;
  const int phase = j / bpl;              // 0..3
  const int within = j - phase * bpl;
  const int l = xcd + (phase << 3);

  const float scale = (float)((double)(1ULL << l) - 1.0);
  const uint32_t r = 1u << l;             // == reference res for these params
  const bool dense = (l <= 6);            // res^3 <= T  <=>  l <= 6
  const v2f* __restrict__ embl = (const v2f*)(emb + ((size_t)l << (LOG2T + 1)));

  #pragma unroll
  for (int k = 0; k < 4; ++k) {
    int li = within * 1024 + k * 256 + (int)threadIdx.x;
    if (li < count) {
      int p = offset + li;
      float xv = __builtin_nontemporal_load(&x[3 * p + 0]);
      float yv = __builtin_nontemporal_load(&x[3 * p + 1]);
      float zv = __builtin_nontemporal_load(&x[3 * p + 2]);
      // EXACT replication of reference rounding: mul RN then add RN (no FMA!)
      float px = __fadd_rn(__fmul_rn(xv, scale), 0.5f);
      float py = __fadd_rn(__fmul_rn(yv, scale), 0.5f);
      float pz = __fadd_rn(__fmul_rn(zv, scale), 0.5f);
      float bx = floorf(px), by = floorf(py), bz = floorf(pz);
      float fx = __fsub_rn(px, bx), fy = __fsub_rn(py, by), fz = __fsub_rn(pz, bz);
      uint32_t gx = (uint32_t)bx, gy = (uint32_t)by, gz = (uint32_t)bz;
      float wx0 = __fsub_rn(1.0f, fx), wx1 = fx;
      float wy0 = __fsub_rn(1.0f, fy), wy1 = fy;
      float wz0 = __fsub_rn(1.0f, fz), wz1 = fz;

      float f0 = 0.0f, f1 = 0.0f;
      #pragma unroll
      for (int c = 0; c < 8; ++c) {
        uint32_t cx = gx + (uint32_t)(c & 1);
        uint32_t cy = gy + (uint32_t)((c >> 1) & 1);
        uint32_t cz = gz + (uint32_t)((c >> 2) & 1);
        uint32_t idx;
        if (dense) idx = cx + cy * r + cz * (r * r);
        else       idx = cx ^ (cy * 2654435761u) ^ (cz * 805459861u);
        idx &= TMASK;
        v2f e = embl[idx];
        float w = ((c & 1) ? wx1 : wx0);
        w = __fmul_rn(w, ((c >> 1) & 1) ? wy1 : wy0);
        w = __fmul_rn(w, ((c >> 2) & 1) ? wz1 : wz0);
        f0 = fmaf(w, e[0], f0);
        f1 = fmaf(w, e[1], f1);
      }
      __builtin_nontemporal_store(pack_bf16(f0, f1),
                                  &feats[(size_t)l * (size_t)chunkCap + li]);
    }
  }
}

__global__ __launch_bounds__(256) void mlp_kernel(
    const uint32_t* __restrict__ feats,
    const float* __restrict__ W1, const float* __restrict__ b1,
    const float* __restrict__ W2, const float* __restrict__ b2,
    const float* __restrict__ W3, const float* __restrict__ b3,
    float* __restrict__ out, int offset, int count, int chunkCap)
{
  // per-thread-column LDS: no cross-thread sharing -> no barriers needed
  __shared__ uint32_t h1p[64][256];  // 64 KiB: 128 bf16 h1 values packed in pairs
  const int tid = (int)threadIdx.x;
  const int li = (int)blockIdx.x * 256 + tid;
  const bool active = (li < count);
  const int lic = active ? li : 0;

  uint32_t fp[32];
  #pragma unroll
  for (int l = 0; l < 32; ++l)
    fp[l] = __builtin_nontemporal_load(&feats[(size_t)l * (size_t)chunkCap + lic]);

  // ---- layer 1: h1 = relu(f @ W1 + b1), in 4 output-chunks of 32 ----
  #pragma clang loop unroll(disable)
  for (int jc = 0; jc < 4; ++jc) {
    const float* __restrict__ W1c = W1 + jc * 32;  // wave-uniform -> scalar loads
    const float* __restrict__ b1c = b1 + jc * 32;
    float acc[32];
    #pragma unroll
    for (int jj = 0; jj < 32; ++jj) acc[jj] = b1c[jj];
    #pragma unroll
    for (int kp = 0; kp < 32; ++kp) {
      uint32_t u = fp[kp];
      float flo = __uint_as_float(u << 16);
      float fhi = __uint_as_float(u & 0xffff0000u);
      #pragma unroll
      for (int jj = 0; jj < 32; ++jj) {
        acc[jj] = fmaf(flo, W1c[(2 * kp) * 128 + jj], acc[jj]);
        acc[jj] = fmaf(fhi, W1c[(2 * kp + 1) * 128 + jj], acc[jj]);
      }
    }
    #pragma unroll
    for (int jj = 0; jj < 32; jj += 2) {
      float a = fmaxf(acc[jj], 0.0f);
      float b = fmaxf(acc[jj + 1], 0.0f);
      h1p[(jc * 32 + jj) >> 1][tid] = pack_bf16(a, b);
    }
  }

  // ---- layer 2 + 3: out = relu(h1 @ W2 + b2) @ W3 + b3, fused ----
  float o = 0.0f;
  #pragma clang loop unroll(disable)
  for (int jc = 0; jc < 4; ++jc) {
    const float* __restrict__ W2c = W2 + jc * 32;
    float acc[32];
    #pragma unroll
    for (int jj = 0; jj < 32; ++jj) acc[jj] = b2[jc * 32 + jj];
    #pragma clang loop unroll_count(2)
    for (int i2 = 0; i2 < 64; ++i2) {
      uint32_t hp = h1p[i2][tid];
      float hlo = __uint_as_float(hp << 16);
      float hhi = __uint_as_float(hp & 0xffff0000u);
      #pragma unroll
      for (int jj = 0; jj < 32; ++jj) {
        acc[jj] = fmaf(hlo, W2c[(2 * i2) * 128 + jj], acc[jj]);
        acc[jj] = fmaf(hhi, W2c[(2 * i2 + 1) * 128 + jj], acc[jj]);
      }
    }
    #pragma unroll
    for (int jj = 0; jj < 32; ++jj)
      o = fmaf(fmaxf(acc[jj], 0.0f), W3[jc * 32 + jj], o);
  }
  if (active) out[offset + li] = o + b3[0];
}

extern "C" void kernel_launch(void* const* d_in, const int* in_sizes, int n_in,
                              void* d_out, int out_size, void* d_ws, size_t ws_size,
                              hipStream_t stream) {
  const float* x   = (const float*)d_in[0];
  const float* emb = (const float*)d_in[1];
  const float* W1  = (const float*)d_in[2];
  const float* b1  = (const float*)d_in[3];
  const float* W2  = (const float*)d_in[4];
  const float* b2  = (const float*)d_in[5];
  const float* W3  = (const float*)d_in[6];
  const float* b3  = (const float*)d_in[7];
  float* out = (float*)d_out;
  const int N = in_sizes[0] / 3;

  uint32_t* feats = (uint32_t*)d_ws;
  const size_t perPoint = (size_t)NLV * sizeof(uint32_t);  // 128 B/point
  size_t capz = ws_size / perPoint;
  if (capz > (size_t)N) capz = (size_t)N;
  int cap = (int)capz & ~1023;
  if (cap <= 0) cap = (N < 1024) ? N : 1024;

  for (int off = 0; off < N; off += cap) {
    int cnt = (N - off < cap) ? (N - off) : cap;
    int bpl = (cnt + 1023) / 1024;          // blocks per level
    encode_kernel<<<32 * bpl, 256, 0, stream>>>(x, emb, feats, off, cnt, cap, bpl);
    mlp_kernel<<<(cnt + 255) / 256, 256, 0, stream>>>(
        feats, W1, b1, W2, b2, W3, b3, out, off, cnt, cap);
  }
}

// Round 5
// 1353.795 us; speedup vs baseline: 1.4522x; 1.4514x over previous
//
#include <hip/hip_runtime.h>
#include <stdint.h>

// Instant-NGP hash-grid + MLP.
// encode: XCD-owned level partitioning (unchanged from round 3; TCP-gather-bound).
// mlp: bf16 MFMA (16x16x32) rewrite. 512 thr / 8 waves / 128 points per block.
//   X transposed into XOR-swizzled LDS; W1/W2 transposed [n][k] bf16 in LDS
//   (W2 in four 32-row k-chunks); layer3 = VALU dot + 16-lane shuffle reduce.

#define NLV 32
#define LOG2T 19
#define TSZ (1u << LOG2T)
#define TMASK (TSZ - 1u)

typedef float v2f __attribute__((ext_vector_type(2)));
typedef float f32x4 __attribute__((ext_vector_type(4)));
typedef short bf16x8 __attribute__((ext_vector_type(8)));
typedef uint32_t u32x4 __attribute__((ext_vector_type(4)));

__device__ __forceinline__ uint32_t pack_bf16(float a, float b) {
  uint32_t ua = __float_as_uint(a), ub = __float_as_uint(b);
  ua = (ua + 0x7fffu + ((ua >> 16) & 1u)) >> 16;
  ub = (ub + 0x7fffu + ((ub >> 16) & 1u)) >> 16;
  return ua | (ub << 16);
}
__device__ __forceinline__ uint16_t bf16_rne(float a) {
  uint32_t u = __float_as_uint(a);
  u = (u + 0x7fffu + ((u >> 16) & 1u)) >> 16;
  return (uint16_t)u;
}

__global__ __launch_bounds__(256) void encode_kernel(
    const float* __restrict__ x, const float* __restrict__ emb,
    uint32_t* __restrict__ feats, int offset, int count, int chunkCap, int bpl)
{
  const int bid = (int)blockIdx.x;
  const int xcd = bid & 7;
  const int j = bid >> 3;
  const int phase = j / bpl;
  const int within = j - phase * bpl;
  const int l = xcd + (phase << 3);

  const float scale = (float)((double)(1ULL << l) - 1.0);
  const uint32_t r = 1u << l;
  const bool dense = (l <= 6);
  const v2f* __restrict__ embl = (const v2f*)(emb + ((size_t)l << (LOG2T + 1)));

  #pragma unroll
  for (int k = 0; k < 4; ++k) {
    int li = within * 1024 + k * 256 + (int)threadIdx.x;
    if (li < count) {
      int p = offset + li;
      float xv = __builtin_nontemporal_load(&x[3 * p + 0]);
      float yv = __builtin_nontemporal_load(&x[3 * p + 1]);
      float zv = __builtin_nontemporal_load(&x[3 * p + 2]);
      // EXACT replication of reference rounding: mul RN then add RN (no FMA!)
      float px = __fadd_rn(__fmul_rn(xv, scale), 0.5f);
      float py = __fadd_rn(__fmul_rn(yv, scale), 0.5f);
      float pz = __fadd_rn(__fmul_rn(zv, scale), 0.5f);
      float bx = floorf(px), by = floorf(py), bz = floorf(pz);
      float fx = __fsub_rn(px, bx), fy = __fsub_rn(py, by), fz = __fsub_rn(pz, bz);
      uint32_t gx = (uint32_t)bx, gy = (uint32_t)by, gz = (uint32_t)bz;
      float wx0 = __fsub_rn(1.0f, fx), wx1 = fx;
      float wy0 = __fsub_rn(1.0f, fy), wy1 = fy;
      float wz0 = __fsub_rn(1.0f, fz), wz1 = fz;

      float f0 = 0.0f, f1 = 0.0f;
      #pragma unroll
      for (int c = 0; c < 8; ++c) {
        uint32_t cx = gx + (uint32_t)(c & 1);
        uint32_t cy = gy + (uint32_t)((c >> 1) & 1);
        uint32_t cz = gz + (uint32_t)((c >> 2) & 1);
        uint32_t idx;
        if (dense) idx = cx + cy * r + cz * (r * r);
        else       idx = cx ^ (cy * 2654435761u) ^ (cz * 805459861u);
        idx &= TMASK;
        v2f e = embl[idx];
        float w = ((c & 1) ? wx1 : wx0);
        w = __fmul_rn(w, ((c >> 1) & 1) ? wy1 : wy0);
        w = __fmul_rn(w, ((c >> 2) & 1) ? wz1 : wz0);
        f0 = fmaf(w, e[0], f0);
        f1 = fmaf(w, e[1], f1);
      }
      __builtin_nontemporal_store(pack_bf16(f0, f1),
                                  &feats[(size_t)l * (size_t)chunkCap + li]);
    }
  }
}

#define MLP_P 128

__global__ __launch_bounds__(512, 4) void mlp_kernel(
    const uint32_t* __restrict__ feats,
    const float* __restrict__ W1, const float* __restrict__ b1,
    const float* __restrict__ W2, const float* __restrict__ b2,
    const float* __restrict__ W3, const float* __restrict__ b3,
    float* __restrict__ out, int offset, int count, int chunkCap)
{
  // LDS: xh [128 pts][256B] (X bf16x64 then h1 bf16x128, XOR-swizzled rows)
  //      wt1 [128 n][128B]  (W1^T bf16, k=0..63)
  //      wb  [128 n][64B]   (W2^T bf16, one 32-k chunk at a time)
  __shared__ char lds[57344];
  char* xh  = lds;
  char* wt1 = lds + 32768;
  char* wb  = lds + 49152;

  const int tid = (int)threadIdx.x;
  const int lane = tid & 63;
  const int w = tid >> 6;        // wave 0..7
  const int col = lane & 15;     // MFMA fragment row/col within 16
  const int kh = lane >> 4;      // k-group 0..3 (8 elems each)
  const int base = (int)blockIdx.x * MLP_P;

  // ---- stage X: 128 points x 32 u32 (level-major global -> point-major LDS)
  {
    int p = tid & 127;
    int q = tid >> 7;            // 0..3
    int gp = base + p;
    int src = (gp < count) ? gp : 0;
    #pragma unroll
    for (int s = 0; s < 2; ++s) {
      int pl = q * 8 + s * 4;    // first of 4 planes
      u32x4 v;
      v.x = __builtin_nontemporal_load(&feats[(size_t)(pl + 0) * chunkCap + src]);
      v.y = __builtin_nontemporal_load(&feats[(size_t)(pl + 1) * chunkCap + src]);
      v.z = __builtin_nontemporal_load(&feats[(size_t)(pl + 2) * chunkCap + src]);
      v.w = __builtin_nontemporal_load(&feats[(size_t)(pl + 3) * chunkCap + src]);
      *(u32x4*)(xh + p * 256 + ((pl * 4) ^ ((p & 7) << 4))) = v;
    }
  }
  // ---- stage WT1 = W1^T bf16 ----
  #pragma unroll
  for (int j = 0; j < 16; ++j) {
    int i = tid + j * 512;       // 0..8191
    int k = i >> 7, n = i & 127;
    *(uint16_t*)(wt1 + n * 128 + ((k * 2) ^ ((n & 7) << 4))) = bf16_rne(W1[i]);
  }
  // ---- stage wb chunk 0 (W2 rows k=0..31) ----
  #pragma unroll
  for (int j = 0; j < 8; ++j) {
    int i = tid + j * 512;       // 0..4095
    int k = i >> 7, n = i & 127;
    *(uint16_t*)(wb + n * 64 + ((k * 2) ^ ((n & 3) << 4))) = bf16_rne(W2[i]);
  }
  __syncthreads();

  // ---- layer 1: h1[p][n] = relu(X @ W1 + b1), p = w*16+col rows per wave ----
  const int p = w * 16 + col;
  f32x4 acc[8];
  #pragma unroll
  for (int nt = 0; nt < 8; ++nt) acc[nt] = {0.f, 0.f, 0.f, 0.f};
  #pragma unroll
  for (int kt = 0; kt < 2; ++kt) {
    bf16x8 a = *(const bf16x8*)(xh + p * 256 + ((kt * 64 + kh * 16) ^ ((p & 7) << 4)));
    #pragma unroll
    for (int nt = 0; nt < 8; ++nt) {
      int n = nt * 16 + col;
      bf16x8 b = *(const bf16x8*)(wt1 + n * 128 + ((kt * 64 + kh * 16) ^ ((n & 7) << 4)));
      acc[nt] = __builtin_amdgcn_mfma_f32_16x16x32_bf16(a, b, acc[nt], 0, 0, 0);
    }
  }
  __syncthreads();  // everyone done reading X before h1 overwrites it

  // write h1 (C/D layout: col=lane&15, row=(lane>>4)*4+reg  [measured])
  #pragma unroll
  for (int nt = 0; nt < 8; ++nt) {
    int n = nt * 16 + col;
    float bias = b1[n];
    #pragma unroll
    for (int rg = 0; rg < 4; ++rg) {
      int pr = w * 16 + kh * 4 + rg;
      float h = fmaxf(acc[nt][rg] + bias, 0.0f);
      *(uint16_t*)(xh + pr * 256 + ((n * 2) ^ ((pr & 7) << 4))) = bf16_rne(h);
    }
  }
  __syncthreads();

  // ---- layer 2: 4 k-chunks of 32, restaging wb between chunks ----
  f32x4 acc2[8];
  #pragma unroll
  for (int nt = 0; nt < 8; ++nt) acc2[nt] = {0.f, 0.f, 0.f, 0.f};
  for (int q = 0; q < 4; ++q) {
    bf16x8 a = *(const bf16x8*)(xh + p * 256 + ((q * 64 + kh * 16) ^ ((p & 7) << 4)));
    #pragma unroll
    for (int nt = 0; nt < 8; ++nt) {
      int n = nt * 16 + col;
      bf16x8 b = *(const bf16x8*)(wb + n * 64 + ((kh * 16) ^ ((n & 3) << 4)));
      acc2[nt] = __builtin_amdgcn_mfma_f32_16x16x32_bf16(a, b, acc2[nt], 0, 0, 0);
    }
    if (q < 3) {
      __syncthreads();  // MFMA reads of wb done
      #pragma unroll
      for (int j = 0; j < 8; ++j) {
        int i = tid + j * 512;
        int k = i >> 7, n = i & 127;
        *(uint16_t*)(wb + n * 64 + ((k * 2) ^ ((n & 3) << 4))) =
            bf16_rne(W2[(size_t)(q + 1) * 4096 + i]);
      }
      __syncthreads();
    }
  }

  // ---- layer 3: out = relu(h2) @ W3 + b3 (VALU + 16-lane butterfly) ----
  float osum[4] = {0.f, 0.f, 0.f, 0.f};
  #pragma unroll
  for (int nt = 0; nt < 8; ++nt) {
    int n = nt * 16 + col;
    float bias = b2[n];
    float w3v = W3[n];
    #pragma unroll
    for (int rg = 0; rg < 4; ++rg)
      osum[rg] = fmaf(fmaxf(acc2[nt][rg] + bias, 0.0f), w3v, osum[rg]);
  }
  #pragma unroll
  for (int rg = 0; rg < 4; ++rg) {
    osum[rg] += __shfl_xor(osum[rg], 1);
    osum[rg] += __shfl_xor(osum[rg], 2);
    osum[rg] += __shfl_xor(osum[rg], 4);
    osum[rg] += __shfl_xor(osum[rg], 8);
  }
  #pragma unroll
  for (int rg = 0; rg < 4; ++rg) {
    if (col == rg) {
      int pr = base + w * 16 + kh * 4 + rg;
      if (pr < count) out[offset + pr] = osum[rg] + b3[0];
    }
  }
}

extern "C" void kernel_launch(void* const* d_in, const int* in_sizes, int n_in,
                              void* d_out, int out_size, void* d_ws, size_t ws_size,
                              hipStream_t stream) {
  const float* x   = (const float*)d_in[0];
  const float* emb = (const float*)d_in[1];
  const float* W1  = (const float*)d_in[2];
  const float* b1  = (const float*)d_in[3];
  const float* W2  = (const float*)d_in[4];
  const float* b2  = (const float*)d_in[5];
  const float* W3  = (const float*)d_in[6];
  const float* b3  = (const float*)d_in[7];
  float* out = (float*)d_out;
  const int N = in_sizes[0] / 3;

  uint32_t* feats = (uint32_t*)d_ws;
  const size_t perPoint = (size_t)NLV * sizeof(uint32_t);  // 128 B/point
  size_t capz = ws_size / perPoint;
  if (capz > (size_t)N) capz = (size_t)N;
  int cap = (int)capz & ~1023;
  if (cap <= 0) cap = (N < 1024) ? N : 1024;

  for (int off = 0; off < N; off += cap) {
    int cnt = (N - off < cap) ? (N - off) : cap;
    int bpl = (cnt + 1023) / 1024;          // blocks per level
    encode_kernel<<<32 * bpl, 256, 0, stream>>>(x, emb, feats, off, cnt, cap, bpl);
    mlp_kernel<<<(cnt + MLP_P - 1) / MLP_P, 512, 0, stream>>>(
        feats, W1, b1, W2, b2, W3, b3, out, off, cnt, cap);
  }
}

// Round 8
// 1010.032 us; speedup vs baseline: 1.9464x; 1.3403x over previous
//
#include <hip/hip_runtime.h>
#include <stdint.h>

// Instant-NGP hash-grid + MLP.
// encode: level-major XCD-owned; corner-PAIR gathers (x-adjacent corners share
//   one 16B load: always for dense levels, when gx even for hash levels).
// prep: W1/W2 -> bf16, pre-swizzled LDS image in d_ws (once per launch).
// mlp: persistent blocks (2048 x ~8 groups of 64 pts), W staged once per block
//   by linear 16B copies, full W2 resident in LDS, MFMA 16x16x32 bf16.

#define NLV 32
#define LOG2T 19
#define TSZ (1u << LOG2T)
#define TMASK (TSZ - 1u)
#define PRIME2 2654435761u
#define PRIME3 805459861u

typedef float v2f __attribute__((ext_vector_type(2)));
typedef float f32x4 __attribute__((ext_vector_type(4)));
typedef float f32x4u __attribute__((ext_vector_type(4), aligned(8)));
typedef short bf16x8 __attribute__((ext_vector_type(8)));
typedef uint32_t u32x4 __attribute__((ext_vector_type(4)));

__device__ __forceinline__ uint32_t pack_bf16(float a, float b) {
  uint32_t ua = __float_as_uint(a), ub = __float_as_uint(b);
  ua = (ua + 0x7fffu + ((ua >> 16) & 1u)) >> 16;
  ub = (ub + 0x7fffu + ((ub >> 16) & 1u)) >> 16;
  return ua | (ub << 16);
}
__device__ __forceinline__ uint16_t bf16_rne(float a) {
  uint32_t u = __float_as_uint(a);
  u = (u + 0x7fffu + ((u >> 16) & 1u)) >> 16;
  return (uint16_t)u;
}

__global__ __launch_bounds__(256) void encode_kernel(
    const float* __restrict__ x, const float* __restrict__ emb,
    uint32_t* __restrict__ feats, int offset, int count, int chunkCap, int bpl)
{
  const int bid = (int)blockIdx.x;
  const int xcd = bid & 7;
  const int j = bid >> 3;
  const int phase = j / bpl;
  const int within = j - phase * bpl;
  const int l = xcd + (phase << 3);

  const float scale = (float)((double)(1ULL << l) - 1.0);
  const uint32_t r = 1u << l, rr = r * r;
  const bool dense = (l <= 6);
  const v2f* __restrict__ embl = (const v2f*)(emb + ((size_t)l << (LOG2T + 1)));

  #pragma unroll
  for (int k = 0; k < 4; ++k) {
    int li = within * 1024 + k * 256 + (int)threadIdx.x;
    if (li < count) {
      int p = offset + li;
      float xv = __builtin_nontemporal_load(&x[3 * p + 0]);
      float yv = __builtin_nontemporal_load(&x[3 * p + 1]);
      float zv = __builtin_nontemporal_load(&x[3 * p + 2]);
      // EXACT replication of reference rounding: mul RN then add RN (no FMA!)
      float px = __fadd_rn(__fmul_rn(xv, scale), 0.5f);
      float py = __fadd_rn(__fmul_rn(yv, scale), 0.5f);
      float pz = __fadd_rn(__fmul_rn(zv, scale), 0.5f);
      float bx = floorf(px), by = floorf(py), bz = floorf(pz);
      float fx = __fsub_rn(px, bx), fy = __fsub_rn(py, by), fz = __fsub_rn(pz, bz);
      uint32_t gx = (uint32_t)bx, gy = (uint32_t)by, gz = (uint32_t)bz;
      float wx0 = __fsub_rn(1.0f, fx), wx1 = fx;
      float wy0 = __fsub_rn(1.0f, fy), wy1 = fy;
      float wz0 = __fsub_rn(1.0f, fz), wz1 = fz;

      float f0 = 0.0f, f1 = 0.0f;
      // 4 (y,z) corner pairs; x-corners merged into one 16B load when adjacent.
      #pragma unroll
      for (int cp = 0; cp < 4; ++cp) {
        uint32_t cy = gy + (uint32_t)(cp & 1);
        uint32_t cz = gz + (uint32_t)(cp >> 1);
        float wyz = __fmul_rn((cp & 1) ? wy1 : wy0, (cp >> 1) ? wz1 : wz0);
        v2f e0, e1;
        if (dense) {
          // idx1 = idx0 + 1: one (possibly 8B-aligned) 16B load
          uint32_t i0 = gx + cy * r + cz * rr;
          f32x4 e2 = *(const f32x4u*)&embl[i0];
          e0[0] = e2.x; e0[1] = e2.y; e1[0] = e2.z; e1[1] = e2.w;
        } else {
          uint32_t h = (cy * PRIME2) ^ (cz * PRIME3);
          uint32_t i0 = (gx ^ h) & TMASK;
          if (!(gx & 1u)) {
            // idx1 = idx0 ^ 1: aligned pair {i0&~1, i0|1}
            f32x4 e2 = *(const f32x4*)&embl[i0 & ~1u];
            bool odd = (i0 & 1u) != 0u;
            e0[0] = odd ? e2.z : e2.x; e0[1] = odd ? e2.w : e2.y;
            e1[0] = odd ? e2.x : e2.z; e1[1] = odd ? e2.y : e2.w;
          } else {
            uint32_t i1 = ((gx + 1u) ^ h) & TMASK;
            e0 = embl[i0];
            e1 = embl[i1];
          }
        }
        float w0 = __fmul_rn(wx0, wyz), w1 = __fmul_rn(wx1, wyz);
        f0 = fmaf(w0, e0[0], f0); f1 = fmaf(w0, e0[1], f1);
        f0 = fmaf(w1, e1[0], f0); f1 = fmaf(w1, e1[1], f1);
      }
      __builtin_nontemporal_store(pack_bf16(f0, f1),
                                  &feats[(size_t)l * (size_t)chunkCap + li]);
    }
  }
}

// W1 -> wimg[0..16KB): [n][64k] bf16, byte addr n*128 + ((k*2)^((n&7)<<4))
// W2 -> wimg[16KB..48KB): [n][128k] bf16, byte addr n*256 + ((k*2)^((n&7)<<4))
__global__ __launch_bounds__(512) void prep_kernel(
    const float* __restrict__ W1, const float* __restrict__ W2,
    uint16_t* __restrict__ wimg)
{
  int i = (int)blockIdx.x * 512 + (int)threadIdx.x;
  if (i < 8192) {
    int k = i >> 7, n = i & 127;
    wimg[(n * 128 + ((k * 2) ^ ((n & 7) << 4))) >> 1] = bf16_rne(W1[i]);
  } else if (i < 24576) {
    int t = i - 8192;
    int k = t >> 7, n = t & 127;
    wimg[(16384 + n * 256 + ((k * 2) ^ ((n & 7) << 4))) >> 1] = bf16_rne(W2[t]);
  }
}

#define MLP_G 64   // points per group

__global__ __launch_bounds__(256, 2) void mlp_kernel(
    const uint32_t* __restrict__ feats, const uint16_t* __restrict__ wimg,
    const float* __restrict__ b1, const float* __restrict__ b2,
    const float* __restrict__ W3, const float* __restrict__ b3,
    float* __restrict__ out, int offset, int count, int chunkCap, int nGroups)
{
  __shared__ char lds[65536];
  char* xh  = lds;           // 64 pts x 256B (X bf16x64 then h1 bf16x128)
  char* wt1 = lds + 16384;   // W1^T image, 16KB
  char* wb  = lds + 32768;   // W2^T image, 32KB (full, resident)

  const int tid = (int)threadIdx.x;
  const int lane = tid & 63;
  const int w = tid >> 6;      // wave 0..3
  const int col = lane & 15;
  const int kh = lane >> 4;

  // stage both W images once per block: straight 16B copies (swizzle is baked)
  #pragma unroll
  for (int jj = 0; jj < 12; ++jj) {
    int i = tid + jj * 256;    // 3072 x 16B = 48KB
    ((u32x4*)wt1)[i] = ((const u32x4*)wimg)[i];
  }

  const int p = w * 16 + col;
  float bias1[8], bias2[8], w3v[8];
  #pragma unroll
  for (int nt = 0; nt < 8; ++nt) {
    int n = nt * 16 + col;
    bias1[nt] = b1[n]; bias2[nt] = b2[n]; w3v[nt] = W3[n];
  }
  const float b3v = b3[0];

  for (int g = (int)blockIdx.x; g < nGroups; g += (int)gridDim.x) {
    const int base = g * MLP_G;
    __syncthreads();  // W image ready / prev group's xh reads drained

    // ---- stage X: 64 points x 32 u32 ----
    {
      int pp = tid & 63, q = tid >> 6;
      int gp = base + pp;
      int src = (gp < count) ? gp : 0;
      #pragma unroll
      for (int s = 0; s < 2; ++s) {
        int pl = q * 8 + s * 4;
        u32x4 v;
        v.x = __builtin_nontemporal_load(&feats[(size_t)(pl + 0) * chunkCap + src]);
        v.y = __builtin_nontemporal_load(&feats[(size_t)(pl + 1) * chunkCap + src]);
        v.z = __builtin_nontemporal_load(&feats[(size_t)(pl + 2) * chunkCap + src]);
        v.w = __builtin_nontemporal_load(&feats[(size_t)(pl + 3) * chunkCap + src]);
        *(u32x4*)(xh + pp * 256 + ((pl * 4) ^ ((pp & 7) << 4))) = v;
      }
    }
    __syncthreads();

    // ---- layer 1 ----
    f32x4 acc[8];
    #pragma unroll
    for (int nt = 0; nt < 8; ++nt) acc[nt] = {0.f, 0.f, 0.f, 0.f};
    #pragma unroll
    for (int kt = 0; kt < 2; ++kt) {
      bf16x8 a = *(const bf16x8*)(xh + p * 256 + ((kt * 64 + kh * 16) ^ ((p & 7) << 4)));
      #pragma unroll
      for (int nt = 0; nt < 8; ++nt) {
        int n = nt * 16 + col;
        bf16x8 b = *(const bf16x8*)(wt1 + n * 128 + ((kt * 64 + kh * 16) ^ ((n & 7) << 4)));
        acc[nt] = __builtin_amdgcn_mfma_f32_16x16x32_bf16(a, b, acc[nt], 0, 0, 0);
      }
    }
    __syncthreads();  // X reads done before h1 overwrites xh

    // h1 -> xh (C/D layout: col=lane&15, row=(lane>>4)*4+reg)
    #pragma unroll
    for (int nt = 0; nt < 8; ++nt) {
      int n = nt * 16 + col;
      #pragma unroll
      for (int rg = 0; rg < 4; ++rg) {
        int pr = w * 16 + kh * 4 + rg;
        float h = fmaxf(acc[nt][rg] + bias1[nt], 0.0f);
        *(uint16_t*)(xh + pr * 256 + ((n * 2) ^ ((pr & 7) << 4))) = bf16_rne(h);
      }
    }
    __syncthreads();

    // ---- layer 2 (full W2 resident) ----
    f32x4 acc2[8];
    #pragma unroll
    for (int nt = 0; nt < 8; ++nt) acc2[nt] = {0.f, 0.f, 0.f, 0.f};
    #pragma unroll
    for (int q = 0; q < 4; ++q) {
      bf16x8 a = *(const bf16x8*)(xh + p * 256 + ((q * 64 + kh * 16) ^ ((p & 7) << 4)));
      #pragma unroll
      for (int nt = 0; nt < 8; ++nt) {
        int n = nt * 16 + col;
        bf16x8 b = *(const bf16x8*)(wb + n * 256 + ((q * 64 + kh * 16) ^ ((n & 7) << 4)));
        acc2[nt] = __builtin_amdgcn_mfma_f32_16x16x32_bf16(a, b, acc2[nt], 0, 0, 0);
      }
    }

    // ---- layer 3 ----
    float osum[4] = {0.f, 0.f, 0.f, 0.f};
    #pragma unroll
    for (int nt = 0; nt < 8; ++nt) {
      #pragma unroll
      for (int rg = 0; rg < 4; ++rg)
        osum[rg] = fmaf(fmaxf(acc2[nt][rg] + bias2[nt], 0.0f), w3v[nt], osum[rg]);
    }
    #pragma unroll
    for (int rg = 0; rg < 4; ++rg) {
      osum[rg] += __shfl_xor(osum[rg], 1);
      osum[rg] += __shfl_xor(osum[rg], 2);
      osum[rg] += __shfl_xor(osum[rg], 4);
      osum[rg] += __shfl_xor(osum[rg], 8);
    }
    #pragma unroll
    for (int rg = 0; rg < 4; ++rg) {
      if (col == rg) {
        int pr = base + w * 16 + kh * 4 + rg;
        if (pr < count) out[offset + pr] = osum[rg] + b3v;
      }
    }
  }
}

extern "C" void kernel_launch(void* const* d_in, const int* in_sizes, int n_in,
                              void* d_out, int out_size, void* d_ws, size_t ws_size,
                              hipStream_t stream) {
  const float* x   = (const float*)d_in[0];
  const float* emb = (const float*)d_in[1];
  const float* W1  = (const float*)d_in[2];
  const float* b1  = (const float*)d_in[3];
  const float* W2  = (const float*)d_in[4];
  const float* b2  = (const float*)d_in[5];
  const float* W3  = (const float*)d_in[6];
  const float* b3  = (const float*)d_in[7];
  float* out = (float*)d_out;
  const int N = in_sizes[0] / 3;

  uint16_t* wimg = (uint16_t*)d_ws;                       // 48KB W image
  uint32_t* feats = (uint32_t*)((char*)d_ws + 49152);
  const size_t perPoint = (size_t)NLV * sizeof(uint32_t); // 128 B/point
  size_t avail = (ws_size > 49152) ? ws_size - 49152 : 0;
  size_t capz = avail / perPoint;
  if (capz > (size_t)N) capz = (size_t)N;
  int cap = (int)capz & ~1023;
  if (cap <= 0) cap = (N < 1024) ? N : 1024;

  prep_kernel<<<48, 512, 0, stream>>>(W1, W2, wimg);

  for (int off = 0; off < N; off += cap) {
    int cnt = (N - off < cap) ? (N - off) : cap;
    int bpl = (cnt + 1023) / 1024;          // blocks per level
    encode_kernel<<<32 * bpl, 256, 0, stream>>>(x, emb, feats, off, cnt, cap, bpl);
    int nGroups = (cnt + MLP_G - 1) / MLP_G;
    int nb = nGroups < 2048 ? nGroups : 2048;
    mlp_kernel<<<nb, 256, 0, stream>>>(
        feats, wimg, b1, b2, W3, b3, out, off, cnt, cap, nGroups);
  }
}